// Round 9
// baseline (43755.490 us; speedup 1.0000x reference)
//
#include <hip/hip_runtime.h>
#include <hip/hip_bf16.h>
#include <hip/hip_fp16.h>

#define VOCABN 50257
#define EMBEDN 256
#define HIDDENN 256
#define TAGSN 8192
#define SEQN 8192

typedef _Float16 half8 __attribute__((ext_vector_type(8)));
typedef float f32x4 __attribute__((ext_vector_type(4)));

__device__ __forceinline__ float sigm(float x) {
    x = fminf(fmaxf(x, -30.f), 30.f);
    return 1.f / (1.f + __expf(-x));
}

__device__ __forceinline__ float tanh_f(float x) {
    x = fminf(fmaxf(x, -15.f), 15.f);
    float e = __expf(-2.f * x);
    return (1.f - e) / (1.f + e);
}

// ---------------------------------------------------------------------------
// prep: WxT[k][o] = W_gate(o)[o&255][k]; bcat[o] = b_gate(o)[o&255]
// ---------------------------------------------------------------------------
__global__ __launch_bounds__(256) void prep_kernel(
    const float* __restrict__ Wf, const float* __restrict__ Wi,
    const float* __restrict__ Wg, const float* __restrict__ Wo,
    const float* __restrict__ bf, const float* __restrict__ bi,
    const float* __restrict__ bg, const float* __restrict__ bo,
    float* __restrict__ WxT, float* __restrict__ bcat)
{
    int idx = blockIdx.x * 256 + threadIdx.x;   // 0..262143
    int k = idx >> 10, o = idx & 1023;
    int g = o >> 8, r = o & 255;
    const float* W = (g == 0) ? Wf : (g == 1) ? Wi : (g == 2) ? Wg : Wo;
    WxT[idx] = W[r * 512 + k];
    if (idx < 1024) {
        const float* b = (g == 0) ? bf : (g == 1) ? bi : (g == 2) ? bg : bo;
        bcat[idx] = b[r];
    }
}

// ---------------------------------------------------------------------------
// xproj[s][o] = sum_k emb[sentence[s]][k] * WxT[k][o] + bcat[o]
// ---------------------------------------------------------------------------
__global__ __launch_bounds__(256) void xproj_kernel(
    const int* __restrict__ sentence, const float* __restrict__ emb,
    const float* __restrict__ WxT, const float* __restrict__ bcat,
    float* __restrict__ xproj)
{
    __shared__ __align__(16) float At[32 * 256];
    const int tid = threadIdx.x;
    const int s0 = blockIdx.y * 32;
    const int o = blockIdx.x * 256 + tid;

#pragma unroll
    for (int i = 0; i < 32; i++) {
        int idx = tid + i * 256;
        int srow = idx >> 8, c = idx & 255;
        At[idx] = emb[(size_t)sentence[s0 + srow] * 256 + c];
    }
    __syncthreads();

    float acc[32];
    float b = bcat[o];
#pragma unroll
    for (int i = 0; i < 32; i++) acc[i] = b;

    for (int k4 = 0; k4 < 64; k4++) {
        float4 w;
        w.x = WxT[(k4 * 4 + 0) * 1024 + o];
        w.y = WxT[(k4 * 4 + 1) * 1024 + o];
        w.z = WxT[(k4 * 4 + 2) * 1024 + o];
        w.w = WxT[(k4 * 4 + 3) * 1024 + o];
#pragma unroll
        for (int i = 0; i < 32; i++) {
            float4 a = *(const float4*)&At[i * 256 + k4 * 4];
            acc[i] += a.x * w.x + a.y * w.y + a.z * w.z + a.w * w.w;
        }
    }
#pragma unroll
    for (int i = 0; i < 32; i++)
        xproj[(size_t)(s0 + i) * 1024 + o] = acc[i];
}

// ---------------------------------------------------------------------------
// Persistent single-workgroup LSTM via MFMA (16x16x32 f16).
// 512 threads = 8 waves. Wave w owns units [32w,32w+32) x 4 gates = 8 tiles.
// r9: all 64 A-frags pinned to AGPRs via inline-asm "a" constraints (r8
// lesson: hipcc won't volunteer >~192 regs to AGPR and spills to scratch
// instead; the "a"-constrained MFMA forces the allocator to assign the
// whole live range to the 256-AGPR file, which MFMA reads natively).
// Accumulators stay in VGPRs ("+v") for the VALU epilogue. LDS per step =
// only 8 hbuf broadcast b128 reads/wave (~770 cy/CU), hidden under the
// 2048-cy MFMA floor. In-wave bpermute epilogue, ONE barrier/step (r6/r7).
// ---------------------------------------------------------------------------
__global__ __launch_bounds__(512, 2) void lstm_kernel(
    const float* __restrict__ Wf, const float* __restrict__ Wi,
    const float* __restrict__ Wg, const float* __restrict__ Wo,
    const float* __restrict__ xproj, float* __restrict__ h_all)
{
    __shared__ __align__(16) _Float16 hbufF[2][256];     // 1 KiB dbuf h (f16)

    const int t = threadIdx.x;
    const int w = t >> 6;          // wave 0..7
    const int l = t & 63;          // lane
    const int row16 = l & 15;      // A row (D col replicated)
    const int kg = l >> 4;         // k-group 0..3

    // ---- one-time setup: all 64 A-frags (forced to AGPRs by use sites) ----
    half8 Areg[64];                // [tile i][kt] = Areg[i*8+kt]
#pragma unroll
    for (int i = 0; i < 8; i++) {
        const int g = i >> 1, p = i & 1;
        const float* W = (g == 0) ? Wf : (g == 1) ? Wi : (g == 2) ? Wg : Wo;
        const int row = 32 * w + 16 * p + row16;
        const float* base = W + row * 512 + 256 + 8 * kg;
#pragma unroll
        for (int kt = 0; kt < 8; kt++) {
            const float* src = base + kt * 32;
            half8 fr;
#pragma unroll
            for (int j = 0; j < 8; j++) fr[j] = (_Float16)src[j];
            Areg[i * 8 + kt] = fr;
        }
    }
    if (t < 256) { hbufF[0][t] = (_Float16)0.f; hbufF[1][t] = (_Float16)0.f; }
    float cst = 0.f;               // cell state: lane v (dup v+32) of wave w -> unit 32w+v

    // epilogue constants
    const int v = l & 31;                                  // unit-within-wave
    const bool phi = (v & 16) != 0;                        // tile half p
    const int srcLane = ((v & 12) << 2) | (phi ? 4 : 0) | (v & 3);
    const int src4 = srcLane << 2;                         // bpermute byte addr
    const bool b1 = (row16 & 1) != 0, b2 = (row16 & 2) != 0;
    const bool pushHi = (row16 & 4) != 0;
    const int u = 32 * w + v;                              // owned unit

    __syncthreads();

    int buf = 0;
    for (int s = 0; s < SEQN; ++s) {
        // xp for the tail (global scalar loads; whole MFMA phase hides them)
        const float* xr = xproj + (size_t)s * 1024;
        float xp0 = xr[u];
        float xp1 = xr[256 + u];
        float xp2 = xr[512 + u];
        float xp3 = xr[768 + u];

        const _Float16* hb = hbufF[buf];
        f32x4 acc[8];
#pragma unroll
        for (int i = 0; i < 8; i++) acc[i] = f32x4{0.f, 0.f, 0.f, 0.f};

#pragma unroll
        for (int kt = 0; kt < 8; kt++) {
            half8 b = *(const half8*)&hb[kt * 32 + kg * 8];
#pragma unroll
            for (int i = 0; i < 8; i++)
                asm("v_mfma_f32_16x16x32_f16 %0, %1, %2, %0"
                    : "+v"(acc[i])
                    : "a"(Areg[i * 8 + kt]), "v"(b));
        }

        // ---- in-wave epilogue ----
        // reg-select j = row16&3: lane then holds row 4kg+j of each tile
        float ai[8];
#pragma unroll
        for (int i = 0; i < 8; i++) {
            float t01 = b1 ? acc[i][1] : acc[i][0];
            float t23 = b1 ? acc[i][3] : acc[i][2];
            ai[i] = b2 ? t23 : t01;
        }
        // per gate: push tile-half by row16&4, one bpermute delivers preact
        float pre[4];
#pragma unroll
        for (int g = 0; g < 4; g++) {
            float push = pushHi ? ai[2 * g + 1] : ai[2 * g];
            pre[g] = __builtin_bit_cast(float,
                __builtin_amdgcn_ds_bpermute(src4, __builtin_bit_cast(int, push)));
        }
        float fg = sigm(pre[0] + xp0);
        float ig = sigm(pre[1] + xp1);
        float gg = tanh_f(pre[2] + xp2);
        float og = sigm(pre[3] + xp3);
        cst = fg * cst + ig * gg;
        float h = og * tanh_f(cst);
        if (l < 32) {
            h_all[s * 256 + u] = h;
            hbufF[buf ^ 1][u] = (_Float16)h;
        }
        __syncthreads();   // new h visible for next step
        buf ^= 1;
    }
}

// ---------------------------------------------------------------------------
// logits[t][v] = h_all[t] . Wtag[v] + btag[v]   (64x64 tile / block, 4x4 micro)
// ---------------------------------------------------------------------------
__global__ __launch_bounds__(256) void logits_kernel(
    const float* __restrict__ h_all, const float* __restrict__ Wtag,
    const float* __restrict__ btag, float* __restrict__ out)
{
    __shared__ __align__(16) float At[64 * 68];
    __shared__ __align__(16) float Bt[64 * 68];
    const int tid = threadIdx.x;
    const int tx = tid & 15, ty = tid >> 4;
    const int t0 = blockIdx.y * 64, v0 = blockIdx.x * 64;
    float acc[4][4] = {};

    for (int kc = 0; kc < 256; kc += 64) {
        __syncthreads();
#pragma unroll
        for (int i = 0; i < 16; i++) {
            int idx = tid + i * 256;
            int rrow = idx >> 6, ccol = idx & 63;
            At[rrow * 68 + ccol] = h_all[(t0 + rrow) * 256 + kc + ccol];
            Bt[rrow * 68 + ccol] = Wtag[(size_t)(v0 + rrow) * 256 + kc + ccol];
        }
        __syncthreads();
#pragma unroll
        for (int k4 = 0; k4 < 16; k4++) {
            float4 av[4], bv[4];
#pragma unroll
            for (int i = 0; i < 4; i++) av[i] = *(const float4*)&At[(ty + 16 * i) * 68 + k4 * 4];
#pragma unroll
            for (int j = 0; j < 4; j++) bv[j] = *(const float4*)&Bt[(tx + 16 * j) * 68 + k4 * 4];
#pragma unroll
            for (int i = 0; i < 4; i++)
#pragma unroll
                for (int j = 0; j < 4; j++)
                    acc[i][j] += av[i].x * bv[j].x + av[i].y * bv[j].y +
                                 av[i].z * bv[j].z + av[i].w * bv[j].w;
        }
    }
#pragma unroll
    for (int j = 0; j < 4; j++) {
        float bb = btag[v0 + tx + 16 * j];
#pragma unroll
        for (int i = 0; i < 4; i++) {
            out[(size_t)(t0 + ty + 16 * i) * TAGSN + v0 + tx + 16 * j] = acc[i][j] + bb;
        }
    }
}

// ---------------------------------------------------------------------------
// in-place row-wise log_softmax over 8192 columns (one block per row)
// ---------------------------------------------------------------------------
__global__ __launch_bounds__(256) void lsm_kernel(float* __restrict__ out)
{
    const int row = blockIdx.x, tid = threadIdx.x;
    float* p = out + (size_t)row * TAGSN;
    float v[32];
#pragma unroll
    for (int j = 0; j < 32; j++) v[j] = p[tid + 256 * j];

    float m = -1e30f;
#pragma unroll
    for (int j = 0; j < 32; j++) m = fmaxf(m, v[j]);
#pragma unroll
    for (int off = 32; off; off >>= 1) m = fmaxf(m, __shfl_xor(m, off, 64));
    __shared__ float red[4];
    if ((tid & 63) == 0) red[tid >> 6] = m;
    __syncthreads();
    m = fmaxf(fmaxf(red[0], red[1]), fmaxf(red[2], red[3]));

    float s = 0.f;
#pragma unroll
    for (int j = 0; j < 32; j++) s += __expf(v[j] - m);
#pragma unroll
    for (int off = 32; off; off >>= 1) s += __shfl_xor(s, off, 64);
    __shared__ float red2[4];
    if ((tid & 63) == 0) red2[tid >> 6] = s;
    __syncthreads();
    s = (red2[0] + red2[1]) + (red2[2] + red2[3]);

    float lse = m + __logf(s);
#pragma unroll
    for (int j = 0; j < 32; j++) p[tid + 256 * j] = v[j] - lse;
}

// ---------------------------------------------------------------------------
extern "C" void kernel_launch(void* const* d_in, const int* in_sizes, int n_in,
                              void* d_out, int out_size, void* d_ws, size_t ws_size,
                              hipStream_t stream)
{
    const int*   sentence = (const int*)d_in[0];
    const float* emb  = (const float*)d_in[1];
    const float* Wf   = (const float*)d_in[2];
    const float* bf   = (const float*)d_in[3];
    const float* Wi   = (const float*)d_in[4];
    const float* bi   = (const float*)d_in[5];
    const float* Wg   = (const float*)d_in[6];
    const float* bg   = (const float*)d_in[7];
    const float* Wo   = (const float*)d_in[8];
    const float* bo   = (const float*)d_in[9];
    const float* Wtag = (const float*)d_in[10];
    const float* btag = (const float*)d_in[11];
    float* out = (float*)d_out;

    char* ws = (char*)d_ws;
    float* WxT   = (float*)(ws);                                      // 1 MiB
    float* bcat  = (float*)(ws + (1u << 20));                         // 4 KiB
    float* xproj = (float*)(ws + (1u << 20) + (1u << 16));            // 32 MiB
    float* h_all = (float*)(ws + (1u << 20) + (1u << 16) + (32u << 20)); // 8 MiB

    prep_kernel<<<1024, 256, 0, stream>>>(Wf, Wi, Wg, Wo, bf, bi, bg, bo, WxT, bcat);
    xproj_kernel<<<dim3(4, 256), 256, 0, stream>>>(sentence, emb, WxT, bcat, xproj);
    lstm_kernel<<<1, 512, 0, stream>>>(Wf, Wi, Wg, Wo, xproj, h_all);
    logits_kernel<<<dim3(128, 128), 256, 0, stream>>>(h_all, Wtag, btag, out);
    lsm_kernel<<<8192, 256, 0, stream>>>(out);
}

// Round 10
// 11349.904 us; speedup vs baseline: 3.8551x; 3.8551x over previous
//
#include <hip/hip_runtime.h>
#include <hip/hip_bf16.h>
#include <hip/hip_fp16.h>

#define VOCABN 50257
#define EMBEDN 256
#define HIDDENN 256
#define TAGSN 8192
#define SEQN 8192

typedef int i32x4 __attribute__((ext_vector_type(4)));

__device__ __forceinline__ float sigm(float x) {
    x = fminf(fmaxf(x, -30.f), 30.f);
    return 1.f / (1.f + __expf(-x));
}

__device__ __forceinline__ float tanh_f(float x) {
    x = fminf(fmaxf(x, -15.f), 15.f);
    float e = __expf(-2.f * x);
    return (1.f - e) / (1.f + e);
}

__device__ __forceinline__ i32x4 mfma_i8(i32x4 a, i32x4 b, i32x4 c) {
#if __has_builtin(__builtin_amdgcn_mfma_i32_16x16x64_i8)
    return __builtin_amdgcn_mfma_i32_16x16x64_i8(a, b, c, 0, 0, 0);
#else
    i32x4 d = c;
    asm("v_mfma_i32_16x16x64_i8 %0, %1, %2, %0" : "+v"(d) : "v"(a), "v"(b));
    return d;
#endif
}

// ---------------------------------------------------------------------------
// prep: WxT[k][o] = W_gate(o)[o&255][k]; bcat[o] = b_gate(o)[o&255]
// ---------------------------------------------------------------------------
__global__ __launch_bounds__(256) void prep_kernel(
    const float* __restrict__ Wf, const float* __restrict__ Wi,
    const float* __restrict__ Wg, const float* __restrict__ Wo,
    const float* __restrict__ bf, const float* __restrict__ bi,
    const float* __restrict__ bg, const float* __restrict__ bo,
    float* __restrict__ WxT, float* __restrict__ bcat)
{
    int idx = blockIdx.x * 256 + threadIdx.x;   // 0..262143
    int k = idx >> 10, o = idx & 1023;
    int g = o >> 8, r = o & 255;
    const float* W = (g == 0) ? Wf : (g == 1) ? Wi : (g == 2) ? Wg : Wo;
    WxT[idx] = W[r * 512 + k];
    if (idx < 1024) {
        const float* b = (g == 0) ? bf : (g == 1) ? bi : (g == 2) ? bg : bo;
        bcat[idx] = b[r];
    }
}

// ---------------------------------------------------------------------------
// xproj[s][o] = sum_k emb[sentence[s]][k] * WxT[k][o] + bcat[o]
// ---------------------------------------------------------------------------
__global__ __launch_bounds__(256) void xproj_kernel(
    const int* __restrict__ sentence, const float* __restrict__ emb,
    const float* __restrict__ WxT, const float* __restrict__ bcat,
    float* __restrict__ xproj)
{
    __shared__ __align__(16) float At[32 * 256];
    const int tid = threadIdx.x;
    const int s0 = blockIdx.y * 32;
    const int o = blockIdx.x * 256 + tid;

#pragma unroll
    for (int i = 0; i < 32; i++) {
        int idx = tid + i * 256;
        int srow = idx >> 8, c = idx & 255;
        At[idx] = emb[(size_t)sentence[s0 + srow] * 256 + c];
    }
    __syncthreads();

    float acc[32];
    float b = bcat[o];
#pragma unroll
    for (int i = 0; i < 32; i++) acc[i] = b;

    for (int k4 = 0; k4 < 64; k4++) {
        float4 w;
        w.x = WxT[(k4 * 4 + 0) * 1024 + o];
        w.y = WxT[(k4 * 4 + 1) * 1024 + o];
        w.z = WxT[(k4 * 4 + 2) * 1024 + o];
        w.w = WxT[(k4 * 4 + 3) * 1024 + o];
#pragma unroll
        for (int i = 0; i < 32; i++) {
            float4 a = *(const float4*)&At[i * 256 + k4 * 4];
            acc[i] += a.x * w.x + a.y * w.y + a.z * w.z + a.w * w.w;
        }
    }
#pragma unroll
    for (int i = 0; i < 32; i++)
        xproj[(size_t)(s0 + i) * 1024 + o] = acc[i];
}

// ---------------------------------------------------------------------------
// Persistent single-workgroup LSTM via int8 MFMA (16x16x64 i8, i32 accum).
// 512 threads = 8 waves. Wave w owns units [32w,32w+32) x 4 gates = 8 tiles.
// Weights quantized per-row symmetric i8 (scale = rowmax/127): ALL weights =
// 32 frags x 4 VGPR = 128 regs/wave (under the 192-reg ceiling proven by
// r5/r8/r9 spills vs r4/r6/r7 fits). h quantized to i8 each step (1/254 abs
// err, h in (-1,1)); accumulation exact in i32; dequant in the epilogue:
// pre = acc * (rowmax/127^2) + xp. MFMA count halves vs f16: 256/step
// (~1300 cy pipe floor). Zero weight-LDS traffic. In-wave bpermute epilogue
// (layout is shape-determined, dtype-independent), ONE barrier/step.
// ---------------------------------------------------------------------------
__global__ __launch_bounds__(512, 2) void lstm_kernel(
    const float* __restrict__ Wf, const float* __restrict__ Wi,
    const float* __restrict__ Wg, const float* __restrict__ Wo,
    const float* __restrict__ xproj, float* __restrict__ h_all)
{
    __shared__ __align__(16) char hb8[2][256];   // dbuf h (i8)
    __shared__ float scLds[4][256];              // rowmax per (gate, unit)

    const int t = threadIdx.x;
    const int w = t >> 6;          // wave 0..7
    const int l = t & 63;          // lane
    const int row16 = l & 15;      // A row (D col replicated)
    const int kg = l >> 4;         // k-group 0..3 (16 bytes each within K=64)

    // ---- one-time setup: per-row maxabs + quantize into 32 i8 frags ----
    i32x4 Areg[32];                // [tile i][kt] = Areg[i*4+kt], kt: K=64 chunks
#pragma unroll
    for (int i = 0; i < 8; i++) {
        const int g = i >> 1, p = i & 1;
        const float* W = (g == 0) ? Wf : (g == 1) ? Wi : (g == 2) ? Wg : Wo;
        const int row = 32 * w + 16 * p + row16;
        const float* base = W + row * 512 + 256;   // h-part of the row

        // pass 1: maxabs over this lane's 64 elems (k = kt*64 + kg*16 + j)
        float mx = 0.f;
#pragma unroll
        for (int kt = 0; kt < 4; kt++)
#pragma unroll
            for (int q = 0; q < 4; q++) {
                float4 v4 = *(const float4*)&base[kt * 64 + kg * 16 + 4 * q];
                mx = fmaxf(mx, fmaxf(fmaxf(fabsf(v4.x), fabsf(v4.y)),
                                     fmaxf(fabsf(v4.z), fabsf(v4.w))));
            }
        // combine across the 4 kg lanes (same row16)
        mx = fmaxf(mx, __shfl_xor(mx, 16, 64));
        mx = fmaxf(mx, __shfl_xor(mx, 32, 64));
        mx = fmaxf(mx, 1e-20f);
        const float inv = 127.f / mx;

        // pass 2: quantize & pack (linear k order; A/B share it -> exact dot)
#pragma unroll
        for (int kt = 0; kt < 4; kt++) {
            unsigned int r[4];
#pragma unroll
            for (int q = 0; q < 4; q++) {
                float4 v4 = *(const float4*)&base[kt * 64 + kg * 16 + 4 * q];
                unsigned int b0 = (unsigned int)(__float2int_rn(v4.x * inv) & 255);
                unsigned int b1 = (unsigned int)(__float2int_rn(v4.y * inv) & 255);
                unsigned int b2 = (unsigned int)(__float2int_rn(v4.z * inv) & 255);
                unsigned int b3 = (unsigned int)(__float2int_rn(v4.w * inv) & 255);
                r[q] = b0 | (b1 << 8) | (b2 << 16) | (b3 << 24);
            }
            Areg[i * 4 + kt] = i32x4{(int)r[0], (int)r[1], (int)r[2], (int)r[3]};
        }
        if (kg == 0) scLds[g][row] = mx;           // publish rowmax
    }
    if (t < 256) { hb8[0][t] = 0; hb8[1][t] = 0; }
    float cst = 0.f;               // cell state: lane v (dup v+32) of wave w -> unit 32w+v

    // epilogue constants
    const int v = l & 31;                                  // unit-within-wave
    const bool phi = (v & 16) != 0;                        // tile half p
    const int srcLane = ((v & 12) << 2) | (phi ? 4 : 0) | (v & 3);
    const int src4 = srcLane << 2;                         // bpermute byte addr
    const bool selA = (row16 & 1) != 0, selB = (row16 & 2) != 0;
    const bool pushHi = (row16 & 4) != 0;
    const int u = 32 * w + v;                              // owned unit

    __syncthreads();

    // per-lane dequant scales (rowmax / 127^2), for the 4 gates of unit u
    const float qs = 1.f / (127.f * 127.f);
    float scl[4];
#pragma unroll
    for (int g = 0; g < 4; g++) scl[g] = scLds[g][u] * qs;

    int buf = 0;
    for (int s = 0; s < SEQN; ++s) {
        // xp for the tail (global scalar loads; MFMA phase hides them)
        const float* xr = xproj + (size_t)s * 1024;
        float xp0 = xr[u];
        float xp1 = xr[256 + u];
        float xp2 = xr[512 + u];
        float xp3 = xr[768 + u];

        const char* hb = hb8[buf];
        i32x4 acc[8];
        const i32x4 z = {0, 0, 0, 0};

        // kt0 (C = shared zero)
        {
            i32x4 b = *(const i32x4*)&hb[0 * 64 + kg * 16];
#pragma unroll
            for (int i = 0; i < 8; i++)
                acc[i] = mfma_i8(Areg[i * 4 + 0], b, z);
        }
#pragma unroll
        for (int kt = 1; kt < 4; kt++) {
            i32x4 b = *(const i32x4*)&hb[kt * 64 + kg * 16];
#pragma unroll
            for (int i = 0; i < 8; i++)
                acc[i] = mfma_i8(Areg[i * 4 + kt], b, acc[i]);
        }

        // ---- in-wave epilogue (i32 accs) ----
        // reg-select j = row16&3: lane then holds row 4kg+j of each tile
        int ai[8];
#pragma unroll
        for (int i = 0; i < 8; i++) {
            int t01 = selA ? acc[i][1] : acc[i][0];
            int t23 = selA ? acc[i][3] : acc[i][2];
            ai[i] = selB ? t23 : t01;
        }
        // per gate: push tile-half by row16&4, one bpermute delivers preact
        float pre[4];
#pragma unroll
        for (int g = 0; g < 4; g++) {
            int push = pushHi ? ai[2 * g + 1] : ai[2 * g];
            pre[g] = (float)__builtin_amdgcn_ds_bpermute(src4, push) * scl[g];
        }
        float fg = sigm(pre[0] + xp0);
        float ig = sigm(pre[1] + xp1);
        float gg = tanh_f(pre[2] + xp2);
        float og = sigm(pre[3] + xp3);
        cst = fg * cst + ig * gg;
        float h = og * tanh_f(cst);
        if (l < 32) {
            h_all[s * 256 + u] = h;
            hb8[buf ^ 1][u] = (char)__float2int_rn(h * 127.f);
        }
        __syncthreads();   // new h visible for next step
        buf ^= 1;
    }
}

// ---------------------------------------------------------------------------
// logits[t][v] = h_all[t] . Wtag[v] + btag[v]   (64x64 tile / block, 4x4 micro)
// ---------------------------------------------------------------------------
__global__ __launch_bounds__(256) void logits_kernel(
    const float* __restrict__ h_all, const float* __restrict__ Wtag,
    const float* __restrict__ btag, float* __restrict__ out)
{
    __shared__ __align__(16) float At[64 * 68];
    __shared__ __align__(16) float Bt[64 * 68];
    const int tid = threadIdx.x;
    const int tx = tid & 15, ty = tid >> 4;
    const int t0 = blockIdx.y * 64, v0 = blockIdx.x * 64;
    float acc[4][4] = {};

    for (int kc = 0; kc < 256; kc += 64) {
        __syncthreads();
#pragma unroll
        for (int i = 0; i < 16; i++) {
            int idx = tid + i * 256;
            int rrow = idx >> 6, ccol = idx & 63;
            At[rrow * 68 + ccol] = h_all[(t0 + rrow) * 256 + kc + ccol];
            Bt[rrow * 68 + ccol] = Wtag[(size_t)(v0 + rrow) * 256 + kc + ccol];
        }
        __syncthreads();
#pragma unroll
        for (int k4 = 0; k4 < 16; k4++) {
            float4 av[4], bv[4];
#pragma unroll
            for (int i = 0; i < 4; i++) av[i] = *(const float4*)&At[(ty + 16 * i) * 68 + k4 * 4];
#pragma unroll
            for (int j = 0; j < 4; j++) bv[j] = *(const float4*)&Bt[(tx + 16 * j) * 68 + k4 * 4];
#pragma unroll
            for (int i = 0; i < 4; i++)
#pragma unroll
                for (int j = 0; j < 4; j++)
                    acc[i][j] += av[i].x * bv[j].x + av[i].y * bv[j].y +
                                 av[i].z * bv[j].z + av[i].w * bv[j].w;
        }
    }
#pragma unroll
    for (int j = 0; j < 4; j++) {
        float bb = btag[v0 + tx + 16 * j];
#pragma unroll
        for (int i = 0; i < 4; i++) {
            out[(size_t)(t0 + ty + 16 * i) * TAGSN + v0 + tx + 16 * j] = acc[i][j] + bb;
        }
    }
}

// ---------------------------------------------------------------------------
// in-place row-wise log_softmax over 8192 columns (one block per row)
// ---------------------------------------------------------------------------
__global__ __launch_bounds__(256) void lsm_kernel(float* __restrict__ out)
{
    const int row = blockIdx.x, tid = threadIdx.x;
    float* p = out + (size_t)row * TAGSN;
    float v[32];
#pragma unroll
    for (int j = 0; j < 32; j++) v[j] = p[tid + 256 * j];

    float m = -1e30f;
#pragma unroll
    for (int j = 0; j < 32; j++) m = fmaxf(m, v[j]);
#pragma unroll
    for (int off = 32; off; off >>= 1) m = fmaxf(m, __shfl_xor(m, off, 64));
    __shared__ float red[4];
    if ((tid & 63) == 0) red[tid >> 6] = m;
    __syncthreads();
    m = fmaxf(fmaxf(red[0], red[1]), fmaxf(red[2], red[3]));

    float s = 0.f;
#pragma unroll
    for (int j = 0; j < 32; j++) s += __expf(v[j] - m);
#pragma unroll
    for (int off = 32; off; off >>= 1) s += __shfl_xor(s, off, 64);
    __shared__ float red2[4];
    if ((tid & 63) == 0) red2[tid >> 6] = s;
    __syncthreads();
    s = (red2[0] + red2[1]) + (red2[2] + red2[3]);

    float lse = m + __logf(s);
#pragma unroll
    for (int j = 0; j < 32; j++) p[tid + 256 * j] = v[j] - lse;
}

// ---------------------------------------------------------------------------
extern "C" void kernel_launch(void* const* d_in, const int* in_sizes, int n_in,
                              void* d_out, int out_size, void* d_ws, size_t ws_size,
                              hipStream_t stream)
{
    const int*   sentence = (const int*)d_in[0];
    const float* emb  = (const float*)d_in[1];
    const float* Wf   = (const float*)d_in[2];
    const float* bf   = (const float*)d_in[3];
    const float* Wi   = (const float*)d_in[4];
    const float* bi   = (const float*)d_in[5];
    const float* Wg   = (const float*)d_in[6];
    const float* bg   = (const float*)d_in[7];
    const float* Wo   = (const float*)d_in[8];
    const float* bo   = (const float*)d_in[9];
    const float* Wtag = (const float*)d_in[10];
    const float* btag = (const float*)d_in[11];
    float* out = (float*)d_out;

    char* ws = (char*)d_ws;
    float* WxT   = (float*)(ws);                                      // 1 MiB
    float* bcat  = (float*)(ws + (1u << 20));                         // 4 KiB
    float* xproj = (float*)(ws + (1u << 20) + (1u << 16));            // 32 MiB
    float* h_all = (float*)(ws + (1u << 20) + (1u << 16) + (32u << 20)); // 8 MiB

    prep_kernel<<<1024, 256, 0, stream>>>(Wf, Wi, Wg, Wo, bf, bi, bg, bo, WxT, bcat);
    xproj_kernel<<<dim3(4, 256), 256, 0, stream>>>(sentence, emb, WxT, bcat, xproj);
    lstm_kernel<<<1, 512, 0, stream>>>(Wf, Wi, Wg, Wo, xproj, h_all);
    logits_kernel<<<dim3(128, 128), 256, 0, stream>>>(h_all, Wtag, btag, out);
    lsm_kernel<<<8192, 256, 0, stream>>>(out);
}